// Round 3
// baseline (325.271 us; speedup 1.0000x reference)
//
#include <hip/hip_runtime.h>

#define HW 3136
#define NPOS 12845056   // 16*256*3136

__device__ __forceinline__ unsigned fkey(float f) {
  unsigned u = __float_as_uint(f);
  return (u & 0x80000000u) ? ~u : (u | 0x80000000u);
}
__device__ __forceinline__ float funkey(unsigned u) {
  return __uint_as_float((u & 0x80000000u) ? (u & 0x7FFFFFFFu) : ~u);
}
__device__ __forceinline__ float spikef(float x) {
  return fminf(fmaxf(rintf(x), 0.0f), 4.0f);
}
__device__ __forceinline__ float rdlane(float v, int src) {
  return __int_as_float(__builtin_amdgcn_readlane(__float_as_int(v), src));
}

// ---------------- Kernel 1: transposes + audio pre-projection + init ----------------
// w1t: [k 256][j 128]  (k-major; GEMM1 loads row k as coalesced 512B)
// w2t: [k 128][j2 64]  (k-major; GEMM2 loads row k as coalesced 256B)
__global__ __launch_bounds__(256) void prep_kernel(
    const float* __restrict__ audio, const float* __restrict__ w1,
    const float* __restrict__ b1, const float* __restrict__ w2,
    float* __restrict__ a_pre, float* __restrict__ w1t,
    float* __restrict__ w2t, float* __restrict__ pool,
    unsigned* __restrict__ mm)
{
  __shared__ float au[256];
  const int bx = blockIdx.x, t = threadIdx.x;
  if (bx < 128) {                       // w1 visual half -> w1t[k][j]
    int idx = bx * 256 + t;             // 32768
    int c = idx >> 7, j = idx & 127;
    w1t[idx] = w1[j * 512 + c];
  } else if (bx < 160) {                // w2 -> w2t[k][j2]
    int idx = (bx - 128) * 256 + t;     // 8192
    int k = idx >> 6, j2 = idx & 63;
    w2t[idx] = w2[j2 * 128 + k];
  } else if (bx < 176) {                // a_pre[b][j] = b1[j] + w1[j][256:512].audio[b]
    int b = bx - 160;
    au[t] = audio[b * 256 + t];
    __syncthreads();
    int w = t >> 6, l = t & 63;
    float a0 = au[l], a1 = au[l + 64], a2 = au[l + 128], a3 = au[l + 192];
    for (int jj = 0; jj < 32; ++jj) {
      int j = w * 32 + jj;
      const float* row = w1 + j * 512 + 256;
      float s = row[l] * a0 + row[l + 64] * a1 + row[l + 128] * a2 + row[l + 192] * a3;
      #pragma unroll
      for (int off = 32; off; off >>= 1) s += __shfl_xor(s, off);
      if (l == 0) a_pre[b * 128 + j] = s + b1[j];
    }
  } else {
    for (int i = t; i < 4096; i += 256) pool[i] = 0.0f;
    if (t == 0) { mm[0] = 0xFFFFFFFFu; mm[1] = 0u; }
  }
}

// ---------------- Kernel 2: fused MLP + mi + pooling ----------------
// Round-9 operand swap: lane = j-pair (weights = per-lane VGPR stream, coalesced
// rows shared by ALL waves -> L1-hit), fm = wave-uniform s_load (32B/k, 8 SGPR/k
// -> deep scalar pipeline fits). Wave owns 8 positions; LN1/LN2 are wave-local
// shfl trees; h1 stays in registers; GEMM2 broadcast via v_readlane (uniform
// index). LDS = 128B (miL), exactly 1 barrier. Grid 98x16 = 6.1 blocks/CU.
__global__ __launch_bounds__(256, 6) void mlp_kernel(
    const float* __restrict__ fm, const float* __restrict__ w1t,
    const float* __restrict__ w2t, const float* __restrict__ b2,
    const float* __restrict__ w3, const float* __restrict__ b3,
    const float* __restrict__ g1, const float* __restrict__ be1,
    const float* __restrict__ g2, const float* __restrict__ be2,
    const float* __restrict__ a_pre, float* __restrict__ mi_out,
    float* __restrict__ pool, unsigned* __restrict__ mm)
{
  __shared__ float miL[32];

  const int b  = blockIdx.y;
  const int p0 = blockIdx.x * 32;                         // block pos base
  const int t  = threadIdx.x;
  const int l  = t & 63;
  const int wv = __builtin_amdgcn_readfirstlane(t >> 6);  // 0..3, uniform
  const int pos0 = p0 + wv * 8;                           // wave pos base (uniform)
  const int j0 = 2 * l;                                   // lane j-pair

  // ---- GEMM1: acc[p][j-pair] = sum_k fm[k][pos0+p] * w1t[k][j0..j0+1] ----
  float acc0[8], acc1[8];
  #pragma unroll
  for (int p = 0; p < 8; ++p) { acc0[p] = 0.f; acc1[p] = 0.f; }
  {
    const float* xrow = fm + (size_t)b * 256 * HW + pos0;   // uniform
    const float* wrow = w1t + j0;                           // per-lane
    #pragma unroll 4
    for (int k = 0; k < 256; ++k) {
      float4 xa = *(const float4*)(xrow + (size_t)k * HW);      // s_load (uniform)
      float4 xb = *(const float4*)(xrow + (size_t)k * HW + 4);  // s_load (uniform)
      float2 w = *(const float2*)(wrow + k * 128);              // coalesced 512B/wave
      acc0[0] = fmaf(xa.x, w.x, acc0[0]); acc1[0] = fmaf(xa.x, w.y, acc1[0]);
      acc0[1] = fmaf(xa.y, w.x, acc0[1]); acc1[1] = fmaf(xa.y, w.y, acc1[1]);
      acc0[2] = fmaf(xa.z, w.x, acc0[2]); acc1[2] = fmaf(xa.z, w.y, acc1[2]);
      acc0[3] = fmaf(xa.w, w.x, acc0[3]); acc1[3] = fmaf(xa.w, w.y, acc1[3]);
      acc0[4] = fmaf(xb.x, w.x, acc0[4]); acc1[4] = fmaf(xb.x, w.y, acc1[4]);
      acc0[5] = fmaf(xb.y, w.x, acc0[5]); acc1[5] = fmaf(xb.y, w.y, acc1[5]);
      acc0[6] = fmaf(xb.z, w.x, acc0[6]); acc1[6] = fmaf(xb.z, w.y, acc1[6]);
      acc0[7] = fmaf(xb.w, w.x, acc0[7]); acc1[7] = fmaf(xb.w, w.y, acc1[7]);
    }
  }
  {   // bias + audio pre-projection (per j)
    float2 ap = *(const float2*)(a_pre + b * 128 + j0);
    #pragma unroll
    for (int p = 0; p < 8; ++p) { acc0[p] += ap.x; acc1[p] += ap.y; }
  }

  // ---- LN1 over j=128 (in-lane pair + 64-lane shfl tree), wave-local ----
  float mu_[8];
  #pragma unroll
  for (int p = 0; p < 8; ++p) {
    float s = acc0[p] + acc1[p];
    #pragma unroll
    for (int off = 32; off; off >>= 1) s += __shfl_xor(s, off);
    mu_[p] = s * (1.0f/128.0f);
  }
  float h1a[8], h1b[8];
  {
    float2 gv = *(const float2*)(g1 + j0);
    float2 bv = *(const float2*)(be1 + j0);
    #pragma unroll
    for (int p = 0; p < 8; ++p) {
      float d0 = acc0[p] - mu_[p], d1 = acc1[p] - mu_[p];
      float s2 = d0 * d0 + d1 * d1;
      #pragma unroll
      for (int off = 32; off; off >>= 1) s2 += __shfl_xor(s2, off);
      float inv = 1.0f / sqrtf(s2 * (1.0f/128.0f) + 1e-5f);
      h1a[p] = spikef(d0 * inv * gv.x + bv.x);
      h1b[p] = spikef(d1 * inv * gv.y + bv.y);
    }
  }

  // ---- GEMM2: acc2[p] per j2=l, broadcast h1 via v_readlane (uniform idx) ----
  float acc2[8];
  #pragma unroll
  for (int p = 0; p < 8; ++p) acc2[p] = 0.f;
  {
    const float* w2base = w2t + l;
    #pragma unroll 2
    for (int kp = 0; kp < 64; ++kp) {       // k2 = 2*kp, 2*kp+1; src lane = kp
      float wA = w2base[(2*kp) * 64];       // coalesced 256B/wave
      float wB = w2base[(2*kp+1) * 64];
      #pragma unroll
      for (int p = 0; p < 8; ++p) {
        float xA = rdlane(h1a[p], kp);
        float xB = rdlane(h1b[p], kp);
        acc2[p] = fmaf(xB, wB, fmaf(xA, wA, acc2[p]));
      }
    }
  }

  // ---- LN2 over j2=64 (shfl tree) + spike + mi ----
  const float b2l = b2[l];
  #pragma unroll
  for (int p = 0; p < 8; ++p) acc2[p] += b2l;
  float miv[8];
  {
    const float g2l = g2[l], be2l = be2[l], w3l = w3[l];
    const float b3v = b3[0];
    #pragma unroll
    for (int p = 0; p < 8; ++p) {
      float s = acc2[p];
      #pragma unroll
      for (int off = 32; off; off >>= 1) s += __shfl_xor(s, off);
      float mu2 = s * (1.0f/64.0f);
      float d = acc2[p] - mu2;
      float s2 = d * d;
      #pragma unroll
      for (int off = 32; off; off >>= 1) s2 += __shfl_xor(s2, off);
      float inv2 = 1.0f / sqrtf(s2 * (1.0f/64.0f) + 1e-5f);
      float sp = spikef(d * inv2 * g2l + be2l) * w3l;
      #pragma unroll
      for (int off = 32; off; off >>= 1) sp += __shfl_xor(sp, off);
      miv[p] = sp + b3v;
    }
  }

  // ---- store mi (lane p writes pos0+p) + miL ----
  {
    float m = 0.f;
    #pragma unroll
    for (int p = 0; p < 8; ++p) m = (l == p) ? miv[p] : m;
    if (l < 8) {
      mi_out[b * HW + pos0 + l] = m;
      miL[wv * 8 + l] = m;
    }
  }
  __syncthreads();

  // ---- global min/max (wave 0, over block's 32 positions) ----
  if (wv == 0) {
    float v = miL[l & 31];
    float mn = v, mx = v;
    #pragma unroll
    for (int off = 16; off; off >>= 1) {
      mn = fminf(mn, __shfl_xor(mn, off));
      mx = fmaxf(mx, __shfl_xor(mx, off));
    }
    if (l == 0) {
      unsigned kmn = fkey(mn), kmx = fkey(mx);
      volatile unsigned* vmm = (volatile unsigned*)mm;
      if (kmn < vmm[0]) atomicMin(&mm[0], kmn);
      if (kmx > vmm[1]) atomicMax(&mm[1], kmx);
    }
  }

  // ---- pooling: pool[b][c] += sum_pos mi[pos]*fm[b][c][pos], 64 c/wave ----
  {
    const int pos = l & 31, ph = l >> 5;
    const float mval = miL[pos];
    const float* fp = fm + ((size_t)(b * 256 + wv * 64 + ph * 32)) * HW + p0 + pos;
    #pragma unroll 4
    for (int ci = 0; ci < 32; ++ci) {
      float v = fp[(size_t)ci * HW] * mval;
      #pragma unroll
      for (int off = 16; off; off >>= 1) v += __shfl_xor(v, off);
      if (pos == 0) atomicAdd(&pool[b * 256 + wv * 64 + ph * 32 + ci], v);
    }
  }
}

// ---------------- Kernel 3: projection + LN + spike -> channel scale ----------------
__global__ __launch_bounds__(256) void scale_kernel(
    const float* __restrict__ pool, const float* __restrict__ pw,
    const float* __restrict__ pb, const float* __restrict__ pg,
    const float* __restrict__ pbeta, float* __restrict__ scale,
    const unsigned* __restrict__ mm, float* __restrict__ gpar)
{
  __shared__ float pl[256];
  __shared__ float xsh[256];
  __shared__ float rs[4], rs2[4];
  int b = blockIdx.x, t = threadIdx.x;
  pl[t] = pool[b*256 + t];
  __syncthreads();
  int w = t >> 6, l = t & 63;
  float p0 = pl[l], p1 = pl[l+64], p2 = pl[l+128], p3 = pl[l+192];
  for (int jj = 0; jj < 64; ++jj) {
    int j = w*64 + jj;
    const float* row = pw + j*256;
    float s = row[l]*p0 + row[l+64]*p1 + row[l+128]*p2 + row[l+192]*p3;
    #pragma unroll
    for (int off = 32; off; off >>= 1) s += __shfl_xor(s, off);
    if (l == 0) xsh[j] = s;
  }
  __syncthreads();
  float x = xsh[t] + pb[t];
  float s = x;
  #pragma unroll
  for (int off = 32; off; off >>= 1) s += __shfl_xor(s, off);
  if (l == 0) rs[w] = s;
  __syncthreads();
  float mu = (rs[0]+rs[1]+rs[2]+rs[3]) * (1.0f/256.0f);
  float d = x - mu;
  float s2 = d*d;
  #pragma unroll
  for (int off = 32; off; off >>= 1) s2 += __shfl_xor(s2, off);
  if (l == 0) rs2[w] = s2;
  __syncthreads();
  float var = (rs2[0]+rs2[1]+rs2[2]+rs2[3]) * (1.0f/256.0f);
  float v = d / sqrtf(var + 1e-5f) * pg[t] + pbeta[t];
  scale[b*256 + t] = spikef(v);
  if (b == 0 && t == 0) {
    float mn = funkey(mm[0]), mx = funkey(mm[1]);
    gpar[0] = mn;
    gpar[1] = mx - mn + 1e-6f;
  }
}

// ---------------- Kernel 4: fusion map + normalized mi map ----------------
__global__ __launch_bounds__(256) void fuse_kernel(
    const float4* __restrict__ fm4, const float* __restrict__ scale,
    const float4* __restrict__ mi4, const float* __restrict__ gpar,
    float4* __restrict__ out4, float4* __restrict__ mi4out)
{
  const int c = blockIdx.x, b = blockIdx.y, t = threadIdx.x;
  if (c < 256) {
    float s = scale[b * 256 + c];
    size_t base = ((size_t)b * 256 + c) * 784;
    #pragma unroll
    for (int i = 0; i < 3; ++i) {
      int idx = t + i * 256;
      float4 v = fm4[base + idx];
      out4[base + idx] = make_float4(v.x*s, v.y*s, v.z*s, v.w*s);
    }
    int idx = t + 768;
    if (idx < 784) {
      float4 v = fm4[base + idx];
      out4[base + idx] = make_float4(v.x*s, v.y*s, v.z*s, v.w*s);
    }
  } else {
    float gmin = gpar[0], den = gpar[1];
    size_t base = (size_t)b * 784;
    #pragma unroll
    for (int i = 0; i < 3; ++i) {
      int idx = t + i * 256;
      float4 v = mi4[base + idx];
      mi4out[base + idx] = make_float4((v.x-gmin)/den, (v.y-gmin)/den,
                                       (v.z-gmin)/den, (v.w-gmin)/den);
    }
    int idx = t + 768;
    if (idx < 784) {
      float4 v = mi4[base + idx];
      mi4out[base + idx] = make_float4((v.x-gmin)/den, (v.y-gmin)/den,
                                       (v.z-gmin)/den, (v.w-gmin)/den);
    }
  }
}

extern "C" void kernel_launch(void* const* d_in, const int* in_sizes, int n_in,
                              void* d_out, int out_size, void* d_ws, size_t ws_size,
                              hipStream_t stream)
{
  const float* fm    = (const float*)d_in[0];
  const float* audio = (const float*)d_in[1];
  const float* w1    = (const float*)d_in[2];
  const float* b1    = (const float*)d_in[3];
  const float* g1    = (const float*)d_in[4];
  const float* be1   = (const float*)d_in[5];
  const float* w2    = (const float*)d_in[6];
  const float* b2    = (const float*)d_in[7];
  const float* g2    = (const float*)d_in[8];
  const float* be2   = (const float*)d_in[9];
  const float* w3    = (const float*)d_in[10];
  const float* b3    = (const float*)d_in[11];
  const float* pw    = (const float*)d_in[12];
  const float* pb    = (const float*)d_in[13];
  const float* pg    = (const float*)d_in[14];
  const float* pbeta = (const float*)d_in[15];

  float* ws    = (float*)d_ws;
  float* a_pre = ws;               // 2048 floats
  float* pool  = ws + 2048;        // 4096
  float* scale = ws + 6144;        // 4096
  float* mi    = ws + 10240;       // 50176 (16B aligned)
  float* w1t   = ws + 60416;       // 32768  [k][j]
  float* w2t   = ws + 93184;       // 8192   [k][j2]
  unsigned* mm = (unsigned*)(ws + 101376);  // 2 keys
  float* gpar  = ws + 101378;      // gmin, denom

  float* out    = (float*)d_out;
  float* mi4out = out + NPOS;

  prep_kernel<<<177, 256, 0, stream>>>(audio, w1, b1, w2, a_pre, w1t, w2t,
                                       pool, mm);
  mlp_kernel<<<dim3(98, 16), 256, 0, stream>>>(fm, w1t, w2t, b2, w3, b3,
                                               g1, be1, g2, be2,
                                               a_pre, mi, pool, mm);
  scale_kernel<<<16, 256, 0, stream>>>(pool, pw, pb, pg, pbeta, scale, mm, gpar);
  fuse_kernel<<<dim3(257, 16), 256, 0, stream>>>((const float4*)fm, scale,
                                                 (const float4*)mi, gpar,
                                                 (float4*)out, (float4*)mi4out);
}